// Round 3
// baseline (3833.772 us; speedup 1.0000x reference)
//
#include <hip/hip_runtime.h>

typedef unsigned short ushort_t;
typedef __attribute__((ext_vector_type(8))) short short8;
typedef __attribute__((ext_vector_type(4))) float floatx4;

#define D_    768
#define SMAX  237
#define S0_   197
#define RPAD  7680   // row allocation (>= 238*32)
#define NHEAD 12
#define BATCH 32

// Activation layout is token-major: row(s,b) = s*32 + b. Dead prompt rows at
// layers >=5 are then contiguous at the top -> M shrinks 7680 -> 6400 there.

__device__ __forceinline__ ushort_t f2bf(float f) {
  union { float f; unsigned u; } v; v.f = f;
  unsigned r = v.u + 0x7FFFu + ((v.u >> 16) & 1u);   // RNE
  return (ushort_t)(r >> 16);
}
__device__ __forceinline__ float bf2f(ushort_t u) {
  union { unsigned u; float f; } v; v.u = ((unsigned)u) << 16; return v.f;
}
__device__ __forceinline__ void async16(const void* g, void* l) {
  __builtin_amdgcn_global_load_lds((const __attribute__((address_space(1))) void*)g,
                                   (__attribute__((address_space(3))) void*)l, 16, 0, 0);
}

// ---------------------------------------------------------------- patchify
__global__ __launch_bounds__(256) void patchify_kernel(
    const float* __restrict__ in, ushort_t* __restrict__ Xp) {
  int rowid = blockIdx.x;                 // 0..6271 = b*196+p
  int b = rowid / 196, p = rowid - b * 196;
  int py = p / 14, px = p - py * 14;
  int tid = threadIdx.x;
#pragma unroll
  for (int t = 0; t < 3; ++t) {
    int k = tid + t * 256;
    int c = k >> 8, rem = k & 255, i = rem >> 4, j = rem & 15;
    float v = in[(((size_t)b * 3 + c) * 224 + py * 16 + i) * 224 + px * 16 + j];
    Xp[(size_t)rowid * 768 + k] = f2bf(v);
  }
}

// ---------------------------------------------------------------- small fills
__global__ void cvt_bf16_kernel(const float* __restrict__ src, ushort_t* __restrict__ dst, int n) {
  int i = blockIdx.x * 256 + threadIdx.x;
  if (i < n) dst[i] = f2bf(src[i]);
}

__global__ void cls_fill_kernel(const float* __restrict__ cls, const float* __restrict__ pos,
                                float* __restrict__ X) {
  int b = blockIdx.x, d = threadIdx.x;    // row(0,b) = b
  X[(size_t)b * 768 + d] = cls[d] + pos[d];
}

__global__ void prompt_fill_kernel(const float* __restrict__ prompts, const float* __restrict__ pos,
                                   const int* __restrict__ eid, float* __restrict__ X, int layer) {
  int id = blockIdx.x;
  int b = id / 40, p = id - b * 40;
  int e = eid[b];
  float v = prompts[(((size_t)layer * 10 + e) * 40 + p) * 768 + threadIdx.x] + pos[threadIdx.x];
  X[((size_t)(197 + p) * 32 + b) * 768 + threadIdx.x] = v;
}

// ---------------------------------------------------------------- weight transpose+cast
__global__ __launch_bounds__(256) void transpose_wts_kernel(
    const float* __restrict__ qkvw, const float* __restrict__ projw,
    const float* __restrict__ fc1w, const float* __restrict__ fc2w,
    ushort_t* __restrict__ wq, ushort_t* __restrict__ wp,
    ushort_t* __restrict__ w1, ushort_t* __restrict__ w2) {
  int id = blockIdx.x;
  const float* src; ushort_t* dst; int K, N, t;
  if (id < 1728)      { src = qkvw; dst = wq; K = 768;  N = 2304; t = id; }
  else if (id < 2304) { src = projw; dst = wp; K = 768;  N = 768;  t = id - 1728; }
  else if (id < 4608) { src = fc1w; dst = w1; K = 768;  N = 3072; t = id - 2304; }
  else                { src = fc2w; dst = w2; K = 3072; N = 768;  t = id - 4608; }
  int ntn = N >> 5;
  int k0 = (t / ntn) * 32, n0 = (t % ntn) * 32;
  __shared__ float tile[32][33];
  int tx = threadIdx.x & 31, ty = threadIdx.x >> 5;
#pragma unroll
  for (int q = 0; q < 4; ++q) {
    int kk = q * 8 + ty;
    tile[kk][tx] = src[(size_t)(k0 + kk) * N + n0 + tx];
  }
  __syncthreads();
#pragma unroll
  for (int q = 0; q < 4; ++q) {
    int nn = q * 8 + ty;
    dst[(size_t)(n0 + nn) * K + k0 + tx] = f2bf(tile[tx][nn]);
  }
}

// ---------------------------------------------------------------- layernorm
__global__ __launch_bounds__(256) void ln_kernel(
    const float* __restrict__ X, const float* __restrict__ s, const float* __restrict__ bt,
    ushort_t* __restrict__ H) {
  int row = blockIdx.x, tid = threadIdx.x;
  const float* xr = X + (size_t)row * 768;
  float v0 = xr[tid], v1 = xr[tid + 256], v2 = xr[tid + 512];
  float sum = v0 + v1 + v2;
  float sq = v0 * v0 + v1 * v1 + v2 * v2;
#pragma unroll
  for (int off = 32; off; off >>= 1) {
    sum += __shfl_down(sum, off, 64);
    sq  += __shfl_down(sq,  off, 64);
  }
  __shared__ float red[8];
  int wv = tid >> 6, ln = tid & 63;
  if (ln == 0) { red[wv] = sum; red[4 + wv] = sq; }
  __syncthreads();
  if (tid == 0) {
    red[0] = red[0] + red[1] + red[2] + red[3];
    red[4] = red[4] + red[5] + red[6] + red[7];
  }
  __syncthreads();
  float mean = red[0] * (1.f / 768.f);
  float var  = red[4] * (1.f / 768.f) - mean * mean;
  float rs = rsqrtf(var + 1e-6f);
  ushort_t* hr = H + (size_t)row * 768;
  hr[tid]       = f2bf((v0 - mean) * rs * s[tid]       + bt[tid]);
  hr[tid + 256] = f2bf((v1 - mean) * rs * s[tid + 256] + bt[tid + 256]);
  hr[tid + 512] = f2bf((v2 - mean) * rs * s[tid + 512] + bt[tid + 512]);
}

// ---------------------------------------------------------------- MFMA GEMM
// 1-D grid (padded to x8) with XCD-contiguous tile swizzle; optional split-K
// (EPI_RESID accumulates via fp32 atomicAdd; bias added only by kz==0).
enum { EPI_BF16 = 0, EPI_GELU = 1, EPI_RESID = 2, EPI_PATCH = 3 };

template <int EPI>
__global__ __launch_bounds__(256) void gemm_kernel(
    const ushort_t* __restrict__ A, int lda,
    const ushort_t* __restrict__ BT, int ldb,
    const float* __restrict__ bias,
    float* __restrict__ XO, ushort_t* __restrict__ O,
    const float* __restrict__ pos,
    int N, int nx, int my, int Klen, int nt) {
  __shared__ ushort_t As[128 * 32];
  __shared__ ushort_t Bs[128 * 32];
  // XCD swizzle: XCD j (= blockIdx%8 round-robin) walks a contiguous tile range
  int per = gridDim.x >> 3;
  int F = blockIdx.x;
  int T = (F & 7) * per + (F >> 3);
  if (T >= nt) return;
  int n_i = T % nx, rest = T / nx;
  int m_i = rest % my, kz = rest / my;
  int m0 = m_i * 128, n0 = n_i * 128;
  int kb = kz * Klen, ke = kb + Klen;

  int tid = threadIdx.x, lane = tid & 63, wv = tid >> 6;
  int wm = (wv >> 1) * 64, wn = (wv & 1) * 64;
  int fr = lane & 15, kg = lane >> 4;
  int sw = (kg ^ ((fr >> 1) & 3)) * 8;       // XOR bank-deswizzle for frag reads

  floatx4 acc[4][4];
#pragma unroll
  for (int i = 0; i < 4; ++i)
#pragma unroll
    for (int j = 0; j < 4; ++j) acc[i][j] = (floatx4){0.f, 0.f, 0.f, 0.f};

  for (int k0 = kb; k0 < ke; k0 += 32) {
#pragma unroll
    for (int t = 0; t < 2; ++t) {
      int flat = (wv * 2 + t) * 64 + lane;      // 0..511
      int row = flat >> 2;
      int ch = ((flat & 3) ^ ((flat >> 3) & 3)) * 8;   // swizzled source chunk
      async16(A + (size_t)(m0 + row) * lda + k0 + ch, &As[(wv * 2 + t) * 512]);
      async16(BT + (size_t)(n0 + row) * ldb + k0 + ch, &Bs[(wv * 2 + t) * 512]);
    }
    __syncthreads();
    short8 af[4], bfr[4];
#pragma unroll
    for (int i = 0; i < 4; ++i) af[i] = *(const short8*)&As[(wm + i * 16 + fr) * 32 + sw];
#pragma unroll
    for (int j = 0; j < 4; ++j) bfr[j] = *(const short8*)&Bs[(wn + j * 16 + fr) * 32 + sw];
#pragma unroll
    for (int i = 0; i < 4; ++i)
#pragma unroll
      for (int j = 0; j < 4; ++j)
        acc[i][j] = __builtin_amdgcn_mfma_f32_16x16x32_bf16(af[i], bfr[j], acc[i][j], 0, 0, 0);
    __syncthreads();
  }

  int rbase = (lane >> 4) * 4;
#pragma unroll
  for (int i = 0; i < 4; ++i) {
#pragma unroll
    for (int j = 0; j < 4; ++j) {
      int col = n0 + wn + j * 16 + fr;
#pragma unroll
      for (int r = 0; r < 4; ++r) {
        int row = m0 + wm + i * 16 + rbase + r;
        if (EPI == EPI_BF16) {
          O[(size_t)row * N + col] = f2bf(acc[i][j][r] + bias[col]);
        } else if (EPI == EPI_GELU) {
          float v = acc[i][j][r] + bias[col];
          float g = 0.5f * v * (1.0f + erff(v * 0.70710678118f));
          O[(size_t)row * N + col] = f2bf(g);
        } else if (EPI == EPI_RESID) {
          float v = acc[i][j][r] + (kz == 0 ? bias[col] : 0.f);
          atomicAdd(&XO[(size_t)row * 768 + col], v);
        } else {  // EPI_PATCH: row = b*196+p -> out row (1+p)*32+b
          int b = row / 196, p = row - b * 196;
          size_t orow = (size_t)(1 + p) * 32 + b;
          XO[orow * 768 + col] = acc[i][j][r] + bias[col] + pos[(size_t)(1 + p) * 768 + col];
        }
      }
    }
  }
}

// ---------------------------------------------------------------- MFMA flash attention
// Token-major rows: row(s,b) = s*32+b. Loads clamp s to S-1 (masked in softmax).
__global__ __launch_bounds__(256) void attn_kernel(ushort_t* __restrict__ qkv, int S) {
  __shared__ ushort_t Kc[64 * 64];
  __shared__ ushort_t Vt[64 * 72];
  __shared__ ushort_t Pb[4][16 * 72];
  int id = blockIdx.x;
  int qc = id & 3, bh = id >> 2;
  int b = bh / NHEAD, h = bh - b * NHEAD;
  int tid = threadIdx.x, lane = tid & 63, wv = tid >> 6;
  int fr = lane & 15, kg = lane >> 4;
  int q0 = qc * 64 + wv * 16;

  int qr = q0 + fr; if (qr > S - 1) qr = S - 1;
  const ushort_t* qp = qkv + ((size_t)qr * 32 + b) * 2304 + h * 64 + kg * 8;
  short8 qf0 = *(const short8*)qp;
  short8 qf1 = *(const short8*)(qp + 32);

  floatx4 oacc[4];
#pragma unroll
  for (int j = 0; j < 4; ++j) oacc[j] = (floatx4){0.f, 0.f, 0.f, 0.f};
  float lsum[4] = {0.f, 0.f, 0.f, 0.f};

  int ksw = kg ^ (fr & 7);
  int kst_g = (lane & 7) ^ ((lane >> 3) & 7);

  for (int c = 0; c < 4; ++c) {
    int key0 = c * 64;
    __syncthreads();
#pragma unroll
    for (int t = 0; t < 2; ++t) {
      int f = (wv * 2 + t) * 64 + lane;
      int kr = key0 + (f >> 3); if (kr > S - 1) kr = S - 1;
      async16(qkv + ((size_t)kr * 32 + b) * 2304 + 768 + h * 64 + kst_g * 8,
              &Kc[(wv * 2 + t) * 512]);
    }
#pragma unroll
    for (int t = 0; t < 2; ++t) {
      int kc = wv * 2 + t;
      int vr = key0 + lane; if (vr > S - 1) vr = S - 1;
      short8 vv = *(const short8*)(qkv + ((size_t)vr * 32 + b) * 2304 + 1536 + h * 64 + kc * 8);
#pragma unroll
      for (int e = 0; e < 8; ++e) Vt[(kc * 8 + e) * 72 + lane] = (ushort_t)vv[e];
    }
    __syncthreads();

    floatx4 sacc[4];
#pragma unroll
    for (int j = 0; j < 4; ++j) sacc[j] = (floatx4){0.f, 0.f, 0.f, 0.f};
#pragma unroll
    for (int j = 0; j < 4; ++j) {
      int krow = j * 16 + fr;
      short8 b0 = *(const short8*)&Kc[krow * 64 + ksw * 8];
      short8 b1 = *(const short8*)&Kc[krow * 64 + (ksw ^ 4) * 8];
      sacc[j] = __builtin_amdgcn_mfma_f32_16x16x32_bf16(qf0, b0, sacc[j], 0, 0, 0);
      sacc[j] = __builtin_amdgcn_mfma_f32_16x16x32_bf16(qf1, b1, sacc[j], 0, 0, 0);
    }

#pragma unroll
    for (int j = 0; j < 4; ++j) {
      int key = key0 + j * 16 + fr;
      bool valid = key < S;
#pragma unroll
      for (int r = 0; r < 4; ++r) {
        float e = valid ? __expf(sacc[j][r] * 0.125f) : 0.f;
        lsum[r] += e;
        Pb[wv][(kg * 4 + r) * 72 + j * 16 + fr] = f2bf(e);
      }
    }
    __syncthreads();

    const ushort_t* pp = &Pb[wv][fr * 72 + kg * 8];
    short8 p0 = *(const short8*)pp;
    short8 p1 = *(const short8*)(pp + 32);
#pragma unroll
    for (int j = 0; j < 4; ++j) {
      const ushort_t* vp = &Vt[(j * 16 + fr) * 72 + kg * 8];
      short8 v0 = *(const short8*)vp;
      short8 v1 = *(const short8*)(vp + 32);
      oacc[j] = __builtin_amdgcn_mfma_f32_16x16x32_bf16(p0, v0, oacc[j], 0, 0, 0);
      oacc[j] = __builtin_amdgcn_mfma_f32_16x16x32_bf16(p1, v1, oacc[j], 0, 0, 0);
    }
  }

#pragma unroll
  for (int r = 0; r < 4; ++r) {
#pragma unroll
    for (int m = 1; m <= 8; m <<= 1) lsum[r] += __shfl_xor(lsum[r], m, 64);
  }
#pragma unroll
  for (int r = 0; r < 4; ++r) {
    int q = q0 + kg * 4 + r;
    if (q < S) {
      float inv = 1.f / lsum[r];
      ushort_t* op = qkv + ((size_t)q * 32 + b) * 2304 + h * 64;
#pragma unroll
      for (int j = 0; j < 4; ++j) op[j * 16 + fr] = f2bf(oacc[j][r] * inv);
    }
  }
}

// ---------------------------------------------------------------- final LN + expert head
__global__ __launch_bounds__(256) void head_kernel(
    const float* __restrict__ X, const float* __restrict__ ns, const float* __restrict__ nb,
    const int* __restrict__ eid, const float* __restrict__ hw, const float* __restrict__ hb,
    float* __restrict__ out) {
  int b = blockIdx.x, tid = threadIdx.x;
  const float* xr = X + (size_t)b * 768;       // row(0,b) = b
  float v0 = xr[tid], v1 = xr[tid + 256], v2 = xr[tid + 512];
  float sum = v0 + v1 + v2;
  float sq = v0 * v0 + v1 * v1 + v2 * v2;
#pragma unroll
  for (int off = 32; off; off >>= 1) {
    sum += __shfl_down(sum, off, 64);
    sq  += __shfl_down(sq,  off, 64);
  }
  __shared__ float red[8];
  __shared__ float feat[768];
  int wv = tid >> 6, ln = tid & 63;
  if (ln == 0) { red[wv] = sum; red[4 + wv] = sq; }
  __syncthreads();
  if (tid == 0) {
    red[0] = red[0] + red[1] + red[2] + red[3];
    red[4] = red[4] + red[5] + red[6] + red[7];
  }
  __syncthreads();
  float mean = red[0] * (1.f / 768.f);
  float var  = red[4] * (1.f / 768.f) - mean * mean;
  float rs = rsqrtf(var + 1e-6f);
  feat[tid]       = (v0 - mean) * rs * ns[tid]       + nb[tid];
  feat[tid + 256] = (v1 - mean) * rs * ns[tid + 256] + nb[tid + 256];
  feat[tid + 512] = (v2 - mean) * rs * ns[tid + 512] + nb[tid + 512];
  __syncthreads();
  int e = eid[b];
  if (tid < 100) {
    float a = hb[e * 100 + tid];
    const float* w = hw + (size_t)e * 768 * 100 + tid;
#pragma unroll 4
    for (int d = 0; d < 768; ++d) a += feat[d] * w[(size_t)d * 100];
    out[b * 100 + tid] = a;
  }
}

// ---------------------------------------------------------------- launcher
extern "C" void kernel_launch(void* const* d_in, const int* in_sizes, int n_in,
                              void* d_out, int out_size, void* d_ws, size_t ws_size,
                              hipStream_t stream) {
  const float* inputs     = (const float*)d_in[0];
  const int*   expert_ids = (const int*)d_in[1];
  const float* patch_w    = (const float*)d_in[2];
  const float* patch_b    = (const float*)d_in[3];
  const float* cls_token  = (const float*)d_in[4];
  const float* pos_embed  = (const float*)d_in[5];
  const float* ln1_s      = (const float*)d_in[6];
  const float* ln1_b      = (const float*)d_in[7];
  const float* qkv_w      = (const float*)d_in[8];
  const float* qkv_b      = (const float*)d_in[9];
  const float* proj_w     = (const float*)d_in[10];
  const float* proj_b     = (const float*)d_in[11];
  const float* ln2_s      = (const float*)d_in[12];
  const float* ln2_b      = (const float*)d_in[13];
  const float* fc1_w      = (const float*)d_in[14];
  const float* fc1_b      = (const float*)d_in[15];
  const float* fc2_w      = (const float*)d_in[16];
  const float* fc2_b      = (const float*)d_in[17];
  const float* norm_s     = (const float*)d_in[18];
  const float* norm_b     = (const float*)d_in[19];
  const float* prompts    = (const float*)d_in[20];
  const float* head_w     = (const float*)d_in[21];
  const float* head_b     = (const float*)d_in[22];
  float* out = (float*)d_out;

  char* ws = (char*)d_ws;
  size_t off = 0;
  ushort_t* WTp = (ushort_t*)(ws + off); off += (size_t)768 * 768 * 2;
  ushort_t* WQ  = (ushort_t*)(ws + off); off += (size_t)2304 * 768 * 2;
  ushort_t* WP  = (ushort_t*)(ws + off); off += (size_t)768 * 768 * 2;
  ushort_t* W1  = (ushort_t*)(ws + off); off += (size_t)3072 * 768 * 2;
  ushort_t* W2  = (ushort_t*)(ws + off); off += (size_t)768 * 3072 * 2;
  float*    X   = (float*)(ws + off);    off += (size_t)RPAD * 768 * 4;
  ushort_t* H   = (ushort_t*)(ws + off); off += (size_t)RPAD * 768 * 2;
  ushort_t* QKV = (ushort_t*)(ws + off); off += (size_t)RPAD * 2304 * 2;
  ushort_t* MID = (ushort_t*)(ws + off); off += (size_t)RPAD * 3072 * 2;
  ushort_t* XP  = MID;   // patchify scratch aliases MID

  cvt_bf16_kernel<<<(768 * 768 + 255) / 256, 256, 0, stream>>>(patch_w, WTp, 768 * 768);
  patchify_kernel<<<6272, 256, 0, stream>>>(inputs, XP);
  {
    int nt = 6 * 49, ntp = ((nt + 7) / 8) * 8;
    gemm_kernel<EPI_PATCH><<<ntp, 256, 0, stream>>>(
        XP, 768, WTp, 768, patch_b, X, nullptr, pos_embed, 768, 6, 49, 768, nt);
  }
  cls_fill_kernel<<<BATCH, 768, 0, stream>>>(cls_token, pos_embed, X);

  for (int i = 0; i < 12; ++i) {
    int S = (i < 5) ? SMAX : S0_;
    int MT = (i < 5) ? 60 : 50;          // m-tiles: ceil(S*32/128)
    if (i < 5)
      prompt_fill_kernel<<<BATCH * 40, 768, 0, stream>>>(prompts, pos_embed, expert_ids, X, i);
    transpose_wts_kernel<<<6912, 256, 0, stream>>>(
        qkv_w + (size_t)i * 768 * 2304, proj_w + (size_t)i * 768 * 768,
        fc1_w + (size_t)i * 768 * 3072, fc2_w + (size_t)i * 3072 * 768,
        WQ, WP, W1, W2);
    ln_kernel<<<MT * 128, 256, 0, stream>>>(X, ln1_s + i * 768, ln1_b + i * 768, H);
    {
      int nt = 18 * MT;
      gemm_kernel<EPI_BF16><<<nt, 256, 0, stream>>>(
          H, 768, WQ, 768, qkv_b + i * 2304, nullptr, QKV, nullptr, 2304, 18, MT, 768, nt);
    }
    attn_kernel<<<BATCH * NHEAD * 4, 256, 0, stream>>>(QKV, S);
    {
      int nt = 6 * MT * 2;   // split-K x2 (384 each)
      gemm_kernel<EPI_RESID><<<nt, 256, 0, stream>>>(
          QKV, 2304, WP, 768, proj_b + i * 768, X, nullptr, nullptr, 768, 6, MT, 384, nt);
    }
    ln_kernel<<<MT * 128, 256, 0, stream>>>(X, ln2_s + i * 768, ln2_b + i * 768, H);
    {
      int nt = 24 * MT;
      gemm_kernel<EPI_GELU><<<nt, 256, 0, stream>>>(
          H, 768, W1, 768, fc1_b + i * 3072, nullptr, MID, nullptr, 3072, 24, MT, 768, nt);
    }
    {
      int nt = 6 * MT * 2;   // split-K x2 (1536 each)
      gemm_kernel<EPI_RESID><<<nt, 256, 0, stream>>>(
          MID, 3072, W2, 3072, fc2_b + i * 768, X, nullptr, nullptr, 768, 6, MT, 1536, nt);
    }
  }

  head_kernel<<<BATCH, 256, 0, stream>>>(X, norm_s, norm_b, expert_ids, head_w, head_b, out);
}

// Round 4
// 3483.591 us; speedup vs baseline: 1.1005x; 1.1005x over previous
//
#include <hip/hip_runtime.h>

typedef unsigned short ushort_t;
typedef __attribute__((ext_vector_type(8))) short short8;
typedef __attribute__((ext_vector_type(4))) float floatx4;

#define D_    768
#define SMAX  237
#define S0_   197
#define RPAD  7680
#define NHEAD 12
#define BATCH 32

// Token-major activations: row(s,b) = s*32 + b. Layers >=5 use M=6400.

__device__ __forceinline__ ushort_t f2bf(float f) {
  union { float f; unsigned u; } v; v.f = f;
  unsigned r = v.u + 0x7FFFu + ((v.u >> 16) & 1u);   // RNE
  return (ushort_t)(r >> 16);
}
__device__ __forceinline__ float bf2f(ushort_t u) {
  union { unsigned u; float f; } v; v.u = ((unsigned)u) << 16; return v.f;
}
__device__ __forceinline__ void async16(const void* g, void* l) {
  __builtin_amdgcn_global_load_lds((const __attribute__((address_space(1))) void*)g,
                                   (__attribute__((address_space(3))) void*)l, 16, 0, 0);
}

// ---------------------------------------------------------------- patchify
__global__ __launch_bounds__(256) void patchify_kernel(
    const float* __restrict__ in, ushort_t* __restrict__ Xp) {
  int rowid = blockIdx.x;                 // 0..6271 = b*196+p
  int b = rowid / 196, p = rowid - b * 196;
  int py = p / 14, px = p - py * 14;
  int tid = threadIdx.x;
#pragma unroll
  for (int t = 0; t < 3; ++t) {
    int k = tid + t * 256;
    int c = k >> 8, rem = k & 255, i = rem >> 4, j = rem & 15;
    float v = in[(((size_t)b * 3 + c) * 224 + py * 16 + i) * 224 + px * 16 + j];
    Xp[(size_t)rowid * 768 + k] = f2bf(v);
  }
}

// ---------------------------------------------------------------- small fills
__global__ void cvt_bf16_kernel(const float* __restrict__ src, ushort_t* __restrict__ dst, int n) {
  int i = blockIdx.x * 256 + threadIdx.x;
  if (i < n) dst[i] = f2bf(src[i]);
}

__global__ void cls_fill_kernel(const float* __restrict__ cls, const float* __restrict__ pos,
                                float* __restrict__ X) {
  int b = blockIdx.x, d = threadIdx.x;    // row(0,b) = b
  X[(size_t)b * 768 + d] = cls[d] + pos[d];
}

__global__ void prompt_fill_kernel(const float* __restrict__ prompts, const float* __restrict__ pos,
                                   const int* __restrict__ eid, float* __restrict__ X, int layer) {
  int id = blockIdx.x;
  int b = id / 40, p = id - b * 40;
  int e = eid[b];
  float v = prompts[(((size_t)layer * 10 + e) * 40 + p) * 768 + threadIdx.x] + pos[threadIdx.x];
  X[((size_t)(197 + p) * 32 + b) * 768 + threadIdx.x] = v;
}

// ---------------------------------------------------------------- weight transpose+cast
// 6912 blocks per layer; l = l0 + id/6912; dst slot = l*slot_mul (0 = shared buf).
__global__ __launch_bounds__(256) void transpose_wts_kernel(
    const float* __restrict__ qkvw, const float* __restrict__ projw,
    const float* __restrict__ fc1w, const float* __restrict__ fc2w,
    ushort_t* __restrict__ wq, ushort_t* __restrict__ wp,
    ushort_t* __restrict__ w1, ushort_t* __restrict__ w2,
    int l0, int slot_mul) {
  int id = blockIdx.x;
  int l = l0 + id / 6912;
  int t = id % 6912;
  size_t s = (size_t)(l * slot_mul);
  const float* src; ushort_t* dst; int K, N;
  if (t < 1728)      { src = qkvw + (size_t)l * 768 * 2304; dst = wq + s * 2304 * 768; K = 768;  N = 2304; }
  else if (t < 2304) { src = projw + (size_t)l * 768 * 768;  dst = wp + s * 768 * 768;  K = 768;  N = 768;  t -= 1728; }
  else if (t < 4608) { src = fc1w + (size_t)l * 768 * 3072;  dst = w1 + s * 768 * 3072; K = 768;  N = 3072; t -= 2304; }
  else               { src = fc2w + (size_t)l * 3072 * 768;  dst = w2 + s * 3072 * 768; K = 3072; N = 768;  t -= 4608; }
  int ntn = N >> 5;
  int k0 = (t / ntn) * 32, n0 = (t % ntn) * 32;
  __shared__ float tile[32][33];
  int tx = threadIdx.x & 31, ty = threadIdx.x >> 5;
#pragma unroll
  for (int q = 0; q < 4; ++q) {
    int kk = q * 8 + ty;
    tile[kk][tx] = src[(size_t)(k0 + kk) * N + n0 + tx];
  }
  __syncthreads();
#pragma unroll
  for (int q = 0; q < 4; ++q) {
    int nn = q * 8 + ty;
    dst[(size_t)(n0 + nn) * K + k0 + tx] = f2bf(tile[tx][nn]);
  }
}

// ---------------------------------------------------------------- layernorm
__global__ __launch_bounds__(256) void ln_kernel(
    const float* __restrict__ X, const float* __restrict__ s, const float* __restrict__ bt,
    ushort_t* __restrict__ H) {
  int row = blockIdx.x, tid = threadIdx.x;
  const float* xr = X + (size_t)row * 768;
  float v0 = xr[tid], v1 = xr[tid + 256], v2 = xr[tid + 512];
  float sum = v0 + v1 + v2;
  float sq = v0 * v0 + v1 * v1 + v2 * v2;
#pragma unroll
  for (int off = 32; off; off >>= 1) {
    sum += __shfl_down(sum, off, 64);
    sq  += __shfl_down(sq,  off, 64);
  }
  __shared__ float red[8];
  int wv = tid >> 6, ln = tid & 63;
  if (ln == 0) { red[wv] = sum; red[4 + wv] = sq; }
  __syncthreads();
  if (tid == 0) {
    red[0] = red[0] + red[1] + red[2] + red[3];
    red[4] = red[4] + red[5] + red[6] + red[7];
  }
  __syncthreads();
  float mean = red[0] * (1.f / 768.f);
  float var  = red[4] * (1.f / 768.f) - mean * mean;
  float rs = rsqrtf(var + 1e-6f);
  ushort_t* hr = H + (size_t)row * 768;
  hr[tid]       = f2bf((v0 - mean) * rs * s[tid]       + bt[tid]);
  hr[tid + 256] = f2bf((v1 - mean) * rs * s[tid + 256] + bt[tid + 256]);
  hr[tid + 512] = f2bf((v2 - mean) * rs * s[tid + 512] + bt[tid + 512]);
}

// ---------------------------------------------------------------- MFMA GEMM epilogues
enum { EPI_BF16 = 0, EPI_GELU = 1, EPI_RESID = 2, EPI_PATCH = 3 };

template <int EPI>
__device__ __forceinline__ void epi_store(float accv, int row, int col,
                                          const float* bias, float* XO, ushort_t* O,
                                          const float* pos, int N) {
  if (EPI == EPI_BF16) {
    O[(size_t)row * N + col] = f2bf(accv + bias[col]);
  } else if (EPI == EPI_GELU) {
    float v = accv + bias[col];
    float g = 0.5f * v * (1.0f + erff(v * 0.70710678118f));
    O[(size_t)row * N + col] = f2bf(g);
  } else if (EPI == EPI_RESID) {
    XO[(size_t)row * 768 + col] += accv + bias[col];
  } else {  // EPI_PATCH: row = b*196+p -> out row (1+p)*32+b
    int b = row / 196, p = row - b * 196;
    size_t orow = (size_t)(1 + p) * 32 + b;
    XO[orow * 768 + col] = accv + bias[col] + pos[(size_t)(1 + p) * 768 + col];
  }
}

// 128x128 tile, BK=32 (wide-N GEMMs: qkv, fc1)
template <int EPI>
__global__ __launch_bounds__(256) void gemm_kernel(
    const ushort_t* __restrict__ A, int lda,
    const ushort_t* __restrict__ BT,
    const float* __restrict__ bias,
    float* __restrict__ XO, ushort_t* __restrict__ O,
    const float* __restrict__ pos,
    int N, int K) {
  __shared__ ushort_t As[128 * 32];
  __shared__ ushort_t Bs[128 * 32];
  int m0 = blockIdx.y * 128, n0 = blockIdx.x * 128;
  int tid = threadIdx.x, lane = tid & 63, wv = tid >> 6;
  int wm = (wv >> 1) * 64, wn = (wv & 1) * 64;
  int fr = lane & 15, kg = lane >> 4;
  int sw = (kg ^ ((fr >> 1) & 3)) * 8;

  floatx4 acc[4][4];
#pragma unroll
  for (int i = 0; i < 4; ++i)
#pragma unroll
    for (int j = 0; j < 4; ++j) acc[i][j] = (floatx4){0.f, 0.f, 0.f, 0.f};

  for (int k0 = 0; k0 < K; k0 += 32) {
#pragma unroll
    for (int t = 0; t < 2; ++t) {
      int flat = (wv * 2 + t) * 64 + lane;
      int row = flat >> 2;
      int ch = ((flat & 3) ^ ((flat >> 3) & 3)) * 8;
      async16(A + (size_t)(m0 + row) * lda + k0 + ch, &As[(wv * 2 + t) * 512]);
      async16(BT + (size_t)(n0 + row) * K + k0 + ch, &Bs[(wv * 2 + t) * 512]);
    }
    __syncthreads();
    short8 af[4], bfr[4];
#pragma unroll
    for (int i = 0; i < 4; ++i) af[i] = *(const short8*)&As[(wm + i * 16 + fr) * 32 + sw];
#pragma unroll
    for (int j = 0; j < 4; ++j) bfr[j] = *(const short8*)&Bs[(wn + j * 16 + fr) * 32 + sw];
#pragma unroll
    for (int i = 0; i < 4; ++i)
#pragma unroll
      for (int j = 0; j < 4; ++j)
        acc[i][j] = __builtin_amdgcn_mfma_f32_16x16x32_bf16(af[i], bfr[j], acc[i][j], 0, 0, 0);
    __syncthreads();
  }

  int rbase = (lane >> 4) * 4;
#pragma unroll
  for (int i = 0; i < 4; ++i)
#pragma unroll
    for (int j = 0; j < 4; ++j) {
      int col = n0 + wn + j * 16 + fr;
#pragma unroll
      for (int r = 0; r < 4; ++r)
        epi_store<EPI>(acc[i][j][r], m0 + wm + i * 16 + rbase + r, col, bias, XO, O, pos, N);
    }
}

// 64x128 tile, BK=32 (narrow-N GEMMs: proj, fc2, patch) -> 2x the blocks
template <int EPI>
__global__ __launch_bounds__(256) void gemm64_kernel(
    const ushort_t* __restrict__ A, int lda,
    const ushort_t* __restrict__ BT,
    const float* __restrict__ bias,
    float* __restrict__ XO, ushort_t* __restrict__ O,
    const float* __restrict__ pos,
    int N, int K) {
  __shared__ ushort_t As[64 * 32];
  __shared__ ushort_t Bs[128 * 32];
  int m0 = blockIdx.y * 64, n0 = blockIdx.x * 128;
  int tid = threadIdx.x, lane = tid & 63, wv = tid >> 6;
  int wm = (wv >> 1) * 32, wn = (wv & 1) * 64;   // 2x2 waves over 64x128
  int fr = lane & 15, kg = lane >> 4;
  int sw = (kg ^ ((fr >> 1) & 3)) * 8;

  floatx4 acc[2][4];
#pragma unroll
  for (int i = 0; i < 2; ++i)
#pragma unroll
    for (int j = 0; j < 4; ++j) acc[i][j] = (floatx4){0.f, 0.f, 0.f, 0.f};

  for (int k0 = 0; k0 < K; k0 += 32) {
    {  // A: 64 rows -> 1 load/thread
      int flat = wv * 64 + lane;
      int row = flat >> 2;
      int ch = ((flat & 3) ^ ((flat >> 3) & 3)) * 8;
      async16(A + (size_t)(m0 + row) * lda + k0 + ch, &As[wv * 512]);
    }
#pragma unroll
    for (int t = 0; t < 2; ++t) {  // B: 128 rows -> 2 loads/thread
      int flat = (wv * 2 + t) * 64 + lane;
      int row = flat >> 2;
      int ch = ((flat & 3) ^ ((flat >> 3) & 3)) * 8;
      async16(BT + (size_t)(n0 + row) * K + k0 + ch, &Bs[(wv * 2 + t) * 512]);
    }
    __syncthreads();
    short8 af[2], bfr[4];
#pragma unroll
    for (int i = 0; i < 2; ++i) af[i] = *(const short8*)&As[(wm + i * 16 + fr) * 32 + sw];
#pragma unroll
    for (int j = 0; j < 4; ++j) bfr[j] = *(const short8*)&Bs[(wn + j * 16 + fr) * 32 + sw];
#pragma unroll
    for (int i = 0; i < 2; ++i)
#pragma unroll
      for (int j = 0; j < 4; ++j)
        acc[i][j] = __builtin_amdgcn_mfma_f32_16x16x32_bf16(af[i], bfr[j], acc[i][j], 0, 0, 0);
    __syncthreads();
  }

  int rbase = (lane >> 4) * 4;
#pragma unroll
  for (int i = 0; i < 2; ++i)
#pragma unroll
    for (int j = 0; j < 4; ++j) {
      int col = n0 + wn + j * 16 + fr;
#pragma unroll
      for (int r = 0; r < 4; ++r)
        epi_store<EPI>(acc[i][j][r], m0 + wm + i * 16 + rbase + r, col, bias, XO, O, pos, N);
    }
}

// ---------------------------------------------------------------- MFMA flash attention
__global__ __launch_bounds__(256) void attn_kernel(ushort_t* __restrict__ qkv, int S) {
  __shared__ ushort_t Kc[64 * 64];
  __shared__ ushort_t Vt[64 * 72];
  __shared__ ushort_t Pb[4][16 * 72];
  int id = blockIdx.x;
  int qc = id & 3, bh = id >> 2;
  int b = bh / NHEAD, h = bh - b * NHEAD;
  int tid = threadIdx.x, lane = tid & 63, wv = tid >> 6;
  int fr = lane & 15, kg = lane >> 4;
  int q0 = qc * 64 + wv * 16;

  int qr = q0 + fr; if (qr > S - 1) qr = S - 1;
  const ushort_t* qp = qkv + ((size_t)qr * 32 + b) * 2304 + h * 64 + kg * 8;
  short8 qf0 = *(const short8*)qp;
  short8 qf1 = *(const short8*)(qp + 32);

  floatx4 oacc[4];
#pragma unroll
  for (int j = 0; j < 4; ++j) oacc[j] = (floatx4){0.f, 0.f, 0.f, 0.f};
  float lsum[4] = {0.f, 0.f, 0.f, 0.f};

  int ksw = kg ^ (fr & 7);
  int kst_g = (lane & 7) ^ ((lane >> 3) & 7);

  for (int c = 0; c < 4; ++c) {
    int key0 = c * 64;
    __syncthreads();
#pragma unroll
    for (int t = 0; t < 2; ++t) {
      int f = (wv * 2 + t) * 64 + lane;
      int kr = key0 + (f >> 3); if (kr > S - 1) kr = S - 1;
      async16(qkv + ((size_t)kr * 32 + b) * 2304 + 768 + h * 64 + kst_g * 8,
              &Kc[(wv * 2 + t) * 512]);
    }
#pragma unroll
    for (int t = 0; t < 2; ++t) {
      int kc = wv * 2 + t;
      int vr = key0 + lane; if (vr > S - 1) vr = S - 1;
      short8 vv = *(const short8*)(qkv + ((size_t)vr * 32 + b) * 2304 + 1536 + h * 64 + kc * 8);
#pragma unroll
      for (int e = 0; e < 8; ++e) Vt[(kc * 8 + e) * 72 + lane] = (ushort_t)vv[e];
    }
    __syncthreads();

    floatx4 sacc[4];
#pragma unroll
    for (int j = 0; j < 4; ++j) sacc[j] = (floatx4){0.f, 0.f, 0.f, 0.f};
#pragma unroll
    for (int j = 0; j < 4; ++j) {
      int krow = j * 16 + fr;
      short8 b0 = *(const short8*)&Kc[krow * 64 + ksw * 8];
      short8 b1 = *(const short8*)&Kc[krow * 64 + (ksw ^ 4) * 8];
      sacc[j] = __builtin_amdgcn_mfma_f32_16x16x32_bf16(qf0, b0, sacc[j], 0, 0, 0);
      sacc[j] = __builtin_amdgcn_mfma_f32_16x16x32_bf16(qf1, b1, sacc[j], 0, 0, 0);
    }

#pragma unroll
    for (int j = 0; j < 4; ++j) {
      int key = key0 + j * 16 + fr;
      bool valid = key < S;
#pragma unroll
      for (int r = 0; r < 4; ++r) {
        float e = valid ? __expf(sacc[j][r] * 0.125f) : 0.f;
        lsum[r] += e;
        Pb[wv][(kg * 4 + r) * 72 + j * 16 + fr] = f2bf(e);
      }
    }
    __syncthreads();

    const ushort_t* pp = &Pb[wv][fr * 72 + kg * 8];
    short8 p0 = *(const short8*)pp;
    short8 p1 = *(const short8*)(pp + 32);
#pragma unroll
    for (int j = 0; j < 4; ++j) {
      const ushort_t* vp = &Vt[(j * 16 + fr) * 72 + kg * 8];
      short8 v0 = *(const short8*)vp;
      short8 v1 = *(const short8*)(vp + 32);
      oacc[j] = __builtin_amdgcn_mfma_f32_16x16x32_bf16(p0, v0, oacc[j], 0, 0, 0);
      oacc[j] = __builtin_amdgcn_mfma_f32_16x16x32_bf16(p1, v1, oacc[j], 0, 0, 0);
    }
  }

#pragma unroll
  for (int r = 0; r < 4; ++r) {
#pragma unroll
    for (int m = 1; m <= 8; m <<= 1) lsum[r] += __shfl_xor(lsum[r], m, 64);
  }
#pragma unroll
  for (int r = 0; r < 4; ++r) {
    int q = q0 + kg * 4 + r;
    if (q < S) {
      float inv = 1.f / lsum[r];
      ushort_t* op = qkv + ((size_t)q * 32 + b) * 2304 + h * 64;
#pragma unroll
      for (int j = 0; j < 4; ++j) op[j * 16 + fr] = f2bf(oacc[j][r] * inv);
    }
  }
}

// ---------------------------------------------------------------- final LN + expert head
__global__ __launch_bounds__(256) void head_kernel(
    const float* __restrict__ X, const float* __restrict__ ns, const float* __restrict__ nb,
    const int* __restrict__ eid, const float* __restrict__ hw, const float* __restrict__ hb,
    float* __restrict__ out) {
  int b = blockIdx.x, tid = threadIdx.x;
  const float* xr = X + (size_t)b * 768;
  float v0 = xr[tid], v1 = xr[tid + 256], v2 = xr[tid + 512];
  float sum = v0 + v1 + v2;
  float sq = v0 * v0 + v1 * v1 + v2 * v2;
#pragma unroll
  for (int off = 32; off; off >>= 1) {
    sum += __shfl_down(sum, off, 64);
    sq  += __shfl_down(sq,  off, 64);
  }
  __shared__ float red[8];
  __shared__ float feat[768];
  int wv = tid >> 6, ln = tid & 63;
  if (ln == 0) { red[wv] = sum; red[4 + wv] = sq; }
  __syncthreads();
  if (tid == 0) {
    red[0] = red[0] + red[1] + red[2] + red[3];
    red[4] = red[4] + red[5] + red[6] + red[7];
  }
  __syncthreads();
  float mean = red[0] * (1.f / 768.f);
  float var  = red[4] * (1.f / 768.f) - mean * mean;
  float rs = rsqrtf(var + 1e-6f);
  feat[tid]       = (v0 - mean) * rs * ns[tid]       + nb[tid];
  feat[tid + 256] = (v1 - mean) * rs * ns[tid + 256] + nb[tid + 256];
  feat[tid + 512] = (v2 - mean) * rs * ns[tid + 512] + nb[tid + 512];
  __syncthreads();
  int e = eid[b];
  if (tid < 100) {
    float a = hb[e * 100 + tid];
    const float* w = hw + (size_t)e * 768 * 100 + tid;
#pragma unroll 4
    for (int d = 0; d < 768; ++d) a += feat[d] * w[(size_t)d * 100];
    out[b * 100 + tid] = a;
  }
}

// ---------------------------------------------------------------- launcher
extern "C" void kernel_launch(void* const* d_in, const int* in_sizes, int n_in,
                              void* d_out, int out_size, void* d_ws, size_t ws_size,
                              hipStream_t stream) {
  const float* inputs     = (const float*)d_in[0];
  const int*   expert_ids = (const int*)d_in[1];
  const float* patch_w    = (const float*)d_in[2];
  const float* patch_b    = (const float*)d_in[3];
  const float* cls_token  = (const float*)d_in[4];
  const float* pos_embed  = (const float*)d_in[5];
  const float* ln1_s      = (const float*)d_in[6];
  const float* ln1_b      = (const float*)d_in[7];
  const float* qkv_w      = (const float*)d_in[8];
  const float* qkv_b      = (const float*)d_in[9];
  const float* proj_w     = (const float*)d_in[10];
  const float* proj_b     = (const float*)d_in[11];
  const float* ln2_s      = (const float*)d_in[12];
  const float* ln2_b      = (const float*)d_in[13];
  const float* fc1_w      = (const float*)d_in[14];
  const float* fc1_b      = (const float*)d_in[15];
  const float* fc2_w      = (const float*)d_in[16];
  const float* fc2_b      = (const float*)d_in[17];
  const float* norm_s     = (const float*)d_in[18];
  const float* norm_b     = (const float*)d_in[19];
  const float* prompts    = (const float*)d_in[20];
  const float* head_w     = (const float*)d_in[21];
  const float* head_b     = (const float*)d_in[22];
  float* out = (float*)d_out;

  // hoist all 12 layers' weight transposes if scratch allows (289 MB)
  const size_t kHoistNeed = 289100000ull;
  bool hoist = ws_size >= kHoistNeed;
  size_t slots = hoist ? 12 : 1;

  char* ws = (char*)d_ws;
  size_t off = 0;
  ushort_t* WTp = (ushort_t*)(ws + off); off += (size_t)768 * 768 * 2;
  ushort_t* WQ  = (ushort_t*)(ws + off); off += slots * 2304 * 768 * 2;
  ushort_t* WP  = (ushort_t*)(ws + off); off += slots * 768 * 768 * 2;
  ushort_t* W1  = (ushort_t*)(ws + off); off += slots * 768 * 3072 * 2;
  ushort_t* W2  = (ushort_t*)(ws + off); off += slots * 3072 * 768 * 2;
  float*    X   = (float*)(ws + off);    off += (size_t)RPAD * 768 * 4;
  ushort_t* H   = (ushort_t*)(ws + off); off += (size_t)RPAD * 768 * 2;
  ushort_t* QKV = (ushort_t*)(ws + off); off += (size_t)RPAD * 2304 * 2;
  ushort_t* MID = (ushort_t*)(ws + off); off += (size_t)RPAD * 3072 * 2;
  ushort_t* XP  = MID;   // patchify scratch aliases MID

  cvt_bf16_kernel<<<(768 * 768 + 255) / 256, 256, 0, stream>>>(patch_w, WTp, 768 * 768);
  patchify_kernel<<<6272, 256, 0, stream>>>(inputs, XP);
  gemm64_kernel<EPI_PATCH><<<dim3(6, 98), 256, 0, stream>>>(
      XP, 768, WTp, patch_b, X, nullptr, pos_embed, 768, 768);
  cls_fill_kernel<<<BATCH, 768, 0, stream>>>(cls_token, pos_embed, X);

  if (hoist)
    transpose_wts_kernel<<<6912 * 12, 256, 0, stream>>>(
        qkv_w, proj_w, fc1_w, fc2_w, WQ, WP, W1, W2, 0, 1);

  for (int i = 0; i < 12; ++i) {
    int S = (i < 5) ? SMAX : S0_;
    int MT = (i < 5) ? 60 : 50;          // m-tiles of 128 (M = 7680 / 6400)
    if (i < 5)
      prompt_fill_kernel<<<BATCH * 40, 768, 0, stream>>>(prompts, pos_embed, expert_ids, X, i);
    if (!hoist)
      transpose_wts_kernel<<<6912, 256, 0, stream>>>(
          qkv_w, proj_w, fc1_w, fc2_w, WQ, WP, W1, W2, i, 0);
    ushort_t* WQi = WQ + (hoist ? (size_t)i * 2304 * 768 : 0);
    ushort_t* WPi = WP + (hoist ? (size_t)i * 768 * 768 : 0);
    ushort_t* W1i = W1 + (hoist ? (size_t)i * 768 * 3072 : 0);
    ushort_t* W2i = W2 + (hoist ? (size_t)i * 3072 * 768 : 0);

    ln_kernel<<<MT * 128, 256, 0, stream>>>(X, ln1_s + i * 768, ln1_b + i * 768, H);
    gemm_kernel<EPI_BF16><<<dim3(18, MT), 256, 0, stream>>>(
        H, 768, WQi, qkv_b + i * 2304, nullptr, QKV, nullptr, 2304, 768);
    attn_kernel<<<BATCH * NHEAD * 4, 256, 0, stream>>>(QKV, S);
    gemm64_kernel<EPI_RESID><<<dim3(6, MT * 2), 256, 0, stream>>>(
        QKV, 2304, WPi, proj_b + i * 768, X, nullptr, nullptr, 768, 768);
    ln_kernel<<<MT * 128, 256, 0, stream>>>(X, ln2_s + i * 768, ln2_b + i * 768, H);
    gemm_kernel<EPI_GELU><<<dim3(24, MT), 256, 0, stream>>>(
        H, 768, W1i, fc1_b + i * 3072, nullptr, MID, nullptr, 3072, 768);
    gemm64_kernel<EPI_RESID><<<dim3(6, MT * 2), 256, 0, stream>>>(
        MID, 3072, W2i, fc2_b + i * 768, X, nullptr, nullptr, 768, 3072);
  }

  head_kernel<<<BATCH, 256, 0, stream>>>(X, norm_s, norm_b, expert_ids, head_w, head_b, out);
}